// Round 1
// baseline (856.274 us; speedup 1.0000x reference)
//
#include <hip/hip_runtime.h>
#include <math.h>

#define QTOT 65536
#define CC 64
#define DD 512
#define KB 16
#define NCHUNK (DD / KB)   /* 32 */
#define BLK 256

/* ws float layout:
   [0] sum c_f   [1] sum c_r   [2] n_r (float count)   [3] masked g_f sum
   [4] masked g_r sum
   [16..80)  |p_r|^2 per rgb proto    [80..144) |p_f|^2 per flow proto
   [256 .. 256+65536)        g_f[i] = c_f[i]*kl_fr[i]
   [256+65536 .. 256+131072) g_r[i] = c_r[i]*kl_rf[i]
   total ~525 KB of d_ws */
enum { WS_SCF = 0, WS_SCR = 1, WS_CNT = 2, WS_MGF = 3, WS_MGR = 4,
       WS_NP = 16, WS_GF = 256, WS_GR = 256 + QTOT };

/* K0: proto row norms (both modalities) + zero the scalar accumulators. */
__global__ __launch_bounds__(64) void k0_norms_zero(
    const float* __restrict__ ctx_r, const float* __restrict__ ctx_f,
    float* ws) {
  const int b = blockIdx.x;        /* 0..127 = modality*64 + proto */
  const int lane = threadIdx.x;    /* 0..63 */
  const float* base = (b < CC) ? ctx_r : ctx_f;
  const int proto = b & (CC - 1);
  const float4* row = (const float4*)(base + (size_t)proto * DD);
  float s = 0.f;
#pragma unroll
  for (int i = 0; i < DD / 4 / 64; ++i) {
    float4 v = row[lane + i * 64];
    s = fmaf(v.x, v.x, s); s = fmaf(v.y, v.y, s);
    s = fmaf(v.z, v.z, s); s = fmaf(v.w, v.w, s);
  }
#pragma unroll
  for (int off = 32; off > 0; off >>= 1) s += __shfl_xor(s, off);
  if (lane == 0) ws[WS_NP + b] = s;
  if (b == 0 && lane < 16) ws[lane] = 0.f;
}

/* K1: fused dual-modality distance GEMM + posterior/entropy/KL/fused-post
   epilogue. One thread per query; protos broadcast via scalar loads. */
__global__ __launch_bounds__(BLK, 1) void k1_main(
    const float* __restrict__ ctx_r, const float* __restrict__ ctx_f,
    const float* __restrict__ tgt_r, const float* __restrict__ tgt_f,
    float* ws, float* __restrict__ out) {
  __shared__ float4 LA[2][4][BLK];   /* 32 KiB staging, [modality][j][query] */
  const int tid = threadIdx.x;
  const int q = blockIdx.x * BLK + tid;

  const float4* tr4 = (const float4*)(tgt_r + (size_t)blockIdx.x * BLK * DD);
  const float4* tf4 = (const float4*)(tgt_f + (size_t)blockIdx.x * BLK * DD);

  float accr[CC], accf[CC];
#pragma unroll
  for (int c = 0; c < CC; ++c) { accr[c] = 0.f; accf[c] = 0.f; }
  float nqr = 0.f, nqf = 0.f;

  /* prefetch registers for the software pipeline */
  float4 pre_r[4], pre_f[4];
#pragma unroll
  for (int i = 0; i < 4; ++i) {
    int f = tid + i * BLK;
    int qr = f >> 2, j = f & 3;
    pre_r[i] = tr4[qr * (DD / 4) + j];
    pre_f[i] = tf4[qr * (DD / 4) + j];
  }

#pragma unroll 1
  for (int kc = 0; kc < NCHUNK; ++kc) {
    __syncthreads();                       /* chunk kc-1 fully consumed */
#pragma unroll
    for (int i = 0; i < 4; ++i) {          /* regs -> LDS (transpose device) */
      int f = tid + i * BLK;
      int qr = f >> 2, j = f & 3;
      LA[0][j][qr] = pre_r[i];
      LA[1][j][qr] = pre_f[i];
    }
    __syncthreads();
    if (kc + 1 < NCHUNK) {                 /* prefetch next chunk (coalesced) */
#pragma unroll
      for (int i = 0; i < 4; ++i) {
        int f = tid + i * BLK;
        int qr = f >> 2, j = f & 3;
        pre_r[i] = tr4[qr * (DD / 4) + (kc + 1) * (KB / 4) + j];
        pre_f[i] = tf4[qr * (DD / 4) + (kc + 1) * (KB / 4) + j];
      }
    }
    /* own query chunk: LDS -> regs (lane-consecutive b128, conflict-free) */
    float qr_[KB], qf_[KB];
#pragma unroll
    for (int j = 0; j < 4; ++j) {
      float4 a = LA[0][j][tid];
      qr_[4 * j] = a.x; qr_[4 * j + 1] = a.y; qr_[4 * j + 2] = a.z; qr_[4 * j + 3] = a.w;
      float4 b = LA[1][j][tid];
      qf_[4 * j] = b.x; qf_[4 * j + 1] = b.y; qf_[4 * j + 2] = b.z; qf_[4 * j + 3] = b.w;
    }
#pragma unroll
    for (int j = 0; j < KB; ++j) {
      nqr = fmaf(qr_[j], qr_[j], nqr);
      nqf = fmaf(qf_[j], qf_[j], nqf);
    }
    /* protos are wave-uniform -> s_load_dwordx16, FMA with SGPR operand */
    const float* Pr = ctx_r + kc * KB;
    const float* Pf = ctx_f + kc * KB;
#pragma unroll
    for (int c = 0; c < CC; ++c) {
      float ar = accr[c], af = accf[c];
#pragma unroll
      for (int j = 0; j < KB; ++j) {
        ar = fmaf(Pr[c * DD + j], qr_[j], ar);
        af = fmaf(Pf[c * DD + j], qf_[j], af);
      }
      accr[c] = ar; accf[c] = af;
    }
  }

  /* ---------------- epilogue: all register-local, zero cross-lane -------- */
  const float* np_r = ws + WS_NP;
  const float* np_f = ws + WS_NP + CC;
  float m = 3.4e38f;
#pragma unroll
  for (int c = 0; c < CC; ++c) {
    float d2r = nqr + np_r[c] - 2.f * accr[c];
    float dr = sqrtf(fmaxf(d2r, 0.f));
    accr[c] = dr;
    float d2f = nqf + np_f[c] - 2.f * accf[c];
    float df = sqrtf(fmaxf(d2f, 0.f));
    accf[c] = df;
    m = fminf(m, fminf(dr, df));
  }
  /* shifted exp: e = exp(m - d); common shift cancels everywhere incl. the
     fused posterior (w_r*e_r + w_f*e_f normalized). */
  float Sr = 0.f, Tr = 0.f, Mr = 0.f, Sf = 0.f, Tf = 0.f, Mf = 0.f;
#pragma unroll
  for (int c = 0; c < CC; ++c) {
    float xr = m - accr[c]; float er = __expf(xr);
    Sr += er; Tr = fmaf(er, xr, Tr); Mr = fmaxf(Mr, er);
    float xf = m - accf[c]; float ef = __expf(xf);
    Sf += ef; Tf = fmaf(ef, xf, Tf); Mf = fmaxf(Mf, ef);
  }
  const float invSr = 1.f / Sr, invSf = 1.f / Sf;
  const float lSr = __logf(Sr), lSf = __logf(Sf);
  const float cr = Mr * invSr, cf = Mf * invSf;          /* confidences   */
  const float hr = lSr - Tr * invSr, hf = lSf - Tf * invSf; /* entropies  */
  const float wr = cr / (cr + cf), wf = cf / (cr + cf);
  const float dinv = 1.f / (wr * Sr + wf * Sf);

  float* out_pf = out + 2;
  float* out_pr = out + 2 + (size_t)QTOT * CC;
  float* out_po = out + 2 + (size_t)2 * QTOT * CC;
  const size_t rowoff = (size_t)q * CC;

  float klfr = 0.f, klrf = 0.f;
#pragma unroll
  for (int c4 = 0; c4 < CC / 4; ++c4) {
    float4 vpf, vpr, vpo;
#pragma unroll
    for (int u = 0; u < 4; ++u) {
      const int c = c4 * 4 + u;
      float xr = m - accr[c]; float er = __expf(xr);
      float xf = m - accf[c]; float ef = __expf(xf);
      float pr = er * invSr, pf = ef * invSf;
      float lpr = xr - lSr, lpf = xf - lSf;   /* exact log p */
      klfr = fmaf(pf, lpf - pr, klfr);        /* faithful: minus p, not log p */
      klrf = fmaf(pr, lpr - pf, klrf);
      float po = (wr * er + wf * ef) * dinv;
      (&vpf.x)[u] = pf; (&vpr.x)[u] = pr; (&vpo.x)[u] = po;
    }
    ((float4*)(out_pf + rowoff))[c4] = vpf;
    ((float4*)(out_pr + rowoff))[c4] = vpr;
    ((float4*)(out_po + rowoff))[c4] = vpo;
  }
  klfr *= (1.f / 64.f); klrf *= (1.f / 64.f);   /* .mean(1) over C=64 */
  ws[WS_GF + q] = cf * klfr;
  ws[WS_GR + q] = cr * klrf;

  const float maskv = (hr > hf && cr > cf) ? 1.f : 0.f;
  float scf = cf, scr = cr, scnt = maskv;
#pragma unroll
  for (int off = 32; off > 0; off >>= 1) {
    scf += __shfl_xor(scf, off);
    scr += __shfl_xor(scr, off);
    scnt += __shfl_xor(scnt, off);
  }
  if ((tid & 63) == 0) {
    atomicAdd(&ws[WS_SCF], scf);
    atomicAdd(&ws[WS_SCR], scr);
    atomicAdd(&ws[WS_CNT], scnt);  /* small integers: exact in fp32 */
  }
}

/* K2: masked sums over g arrays using the global n_r from K1. */
__global__ __launch_bounds__(256) void k2_reduce(float* ws) {
  const int nr = (int)ws[WS_CNT];
  const int nf = QTOT - nr;
  float sf = 0.f, sr = 0.f;
  for (int i = blockIdx.x * 256 + threadIdx.x; i < QTOT;
       i += gridDim.x * 256) {
    if (i < nf) sf += ws[WS_GF + i];
    if (i < nr) sr += ws[WS_GR + i];
  }
#pragma unroll
  for (int off = 32; off > 0; off >>= 1) {
    sf += __shfl_xor(sf, off);
    sr += __shfl_xor(sr, off);
  }
  if ((threadIdx.x & 63) == 0) {
    atomicAdd(&ws[WS_MGF], sf);
    atomicAdd(&ws[WS_MGR], sr);
  }
}

__global__ void k3_final(const float* ws, float* out) {
  if (threadIdx.x == 0) {
    out[0] = ws[WS_MGF] / ws[WS_SCF];
    out[1] = ws[WS_MGR] / ws[WS_SCR];
  }
}

extern "C" void kernel_launch(void* const* d_in, const int* in_sizes, int n_in,
                              void* d_out, int out_size, void* d_ws, size_t ws_size,
                              hipStream_t stream) {
  const float* ctx_r = (const float*)d_in[0];
  const float* ctx_f = (const float*)d_in[1];
  const float* tgt_r = (const float*)d_in[2];
  const float* tgt_f = (const float*)d_in[3];
  float* out = (float*)d_out;
  float* ws = (float*)d_ws;

  k0_norms_zero<<<128, 64, 0, stream>>>(ctx_r, ctx_f, ws);
  k1_main<<<QTOT / BLK, BLK, 0, stream>>>(ctx_r, ctx_f, tgt_r, tgt_f, ws, out);
  k2_reduce<<<64, 256, 0, stream>>>(ws);
  k3_final<<<1, 64, 0, stream>>>(ws, out);
}